// Round 9
// baseline (297.289 us; speedup 1.0000x reference)
//
#include <hip/hip_runtime.h>
#include <hip/hip_bf16.h>

// C[m][o] = sum_i x[m][i] * ternary[o][i] * scales[o*32 + i/128]
// M=8192, N=4096, K=4096. Fused prepass to bf16 (x cvt + W dequant) in d_ws,
// then 256x256 8-phase bf16 NT-GEMM on the R6-verified ledger, with
// R9: v_mfma_f32_32x32x16_bf16 (halved MFMA count, -17% pipe time/tile).
// Phase f handles one 32-row frag (2 subtiles); f's A-half = f>>1 == R6's
// quadrant mapping, so stage slots + vmcnt waits are the R6 ledger verbatim.

#define Msz 8192
#define Nsz 4096
#define Ksz 4096

typedef __attribute__((ext_vector_type(8))) short short8;
typedef __attribute__((ext_vector_type(16))) float f32x16;
typedef __attribute__((ext_vector_type(4))) int int4v;
typedef __attribute__((ext_vector_type(4))) float float4v;
typedef __attribute__((ext_vector_type(8))) unsigned short ushort8;

static __device__ __forceinline__ unsigned short f2bf(float f) {
    unsigned u = __builtin_bit_cast(unsigned, f);
    u += 0x7fffu + ((u >> 16) & 1u);
    return (unsigned short)(u >> 16);
}

// ---------------- fused prepass: blocks [0,2048) cvt x ; [2048,3072) dequant W ----------------
__global__ void prep(const float* __restrict__ x, const int* __restrict__ t,
                     const float* __restrict__ s,
                     unsigned short* __restrict__ ox, unsigned short* __restrict__ ow) {
    if (blockIdx.x < 2048) {
        int i = blockIdx.x * 256 + threadIdx.x;
        for (; i < Msz * Ksz / 8; i += 2048 * 256) {
            const float4v* p = (const float4v*)x + (size_t)i * 2;
            float4v a = p[0], b = p[1];
            ushort8 r;
            r[0] = f2bf(a[0]); r[1] = f2bf(a[1]); r[2] = f2bf(a[2]); r[3] = f2bf(a[3]);
            r[4] = f2bf(b[0]); r[5] = f2bf(b[1]); r[6] = f2bf(b[2]); r[7] = f2bf(b[3]);
            *((ushort8*)ox + i) = r;
        }
    } else {
        int i = (blockIdx.x - 2048) * 256 + threadIdx.x;
        for (; i < Nsz * Ksz / 8; i += 1024 * 256) {
            float sc = s[i >> 4];  // 8-elem chunk stays inside one 128-group
            const int4v* p = (const int4v*)t + (size_t)i * 2;
            int4v a = p[0], b = p[1];
            ushort8 r;
            r[0] = f2bf((float)a[0] * sc); r[1] = f2bf((float)a[1] * sc);
            r[2] = f2bf((float)a[2] * sc); r[3] = f2bf((float)a[3] * sc);
            r[4] = f2bf((float)b[0] * sc); r[5] = f2bf((float)b[1] * sc);
            r[6] = f2bf((float)b[2] * sc); r[7] = f2bf((float)b[3] * sc);
            *((ushort8*)ow + i) = r;
        }
    }
}

// ---------------- main GEMM ----------------
// 8 waves (2M x 4N). Wave (wr,wc): rows = 4 rowfrags f of 32 (rowTiles
// {f*4+wr*2, +1}), cols = 2 colfrags n of 32 (colTiles {wc*4+n*2, +1}).
// LDS: 2 buf x {A 32K, B 32K}; 1KiB subtiles (16 rows x 32 k), idx =
// rowTile*2+ks, XOR-swizzled (bit5 ^= row-bit3; verified R2 involution).
// Frag read (32x32x16, k16 kk): lane l -> row l&31, k=(l>>5)*8; subtile
// rowTile*2+(kk>>1); byte = (laneT) ^ ((kk&1)<<5).
// MFMA: kk-outer/n-inner => 2 indep acc chains, dep distance 2 (m119-peak-ok).

#define READ_B32(b) {                                                            \
    _Pragma("unroll") for (int n = 0; n < 2; ++n)                                \
    _Pragma("unroll") for (int kk = 0; kk < 4; ++kk)                             \
      bf[n][kk] = *(const short8*)(L + (b)*65536 + 32768                         \
        + (((wc*4 + n*2 + hi16)*2 + (kk>>1))<<10) + (laneT ^ ((kk&1)<<5))); }

#define READ_A32(b, f) {                                                         \
    _Pragma("unroll") for (int kk = 0; kk < 4; ++kk)                             \
      af[kk] = *(const short8*)(L + (b)*65536                                    \
        + ((((f)*4 + wr*2 + hi16)*2 + (kk>>1))<<10) + (laneT ^ ((kk&1)<<5))); }

#define MFMAS32(f) {                                                             \
    _Pragma("unroll") for (int kk = 0; kk < 4; ++kk)                             \
    _Pragma("unroll") for (int n = 0; n < 2; ++n)                                \
      acc[f][n] = __builtin_amdgcn_mfma_f32_32x32x16_bf16(af[kk], bf[n][kk], acc[f][n], 0, 0, 0); }

// Stage one M-half (128 rows x K=64 = 16KB) at K-tile T into BOFF+MOFF+H*16384.
#define STAGE_H(PM, MOFF, BOFF, T, H) {                                          \
    _Pragma("unroll") for (int j = 0; j < 2; ++j)                                \
      __builtin_amdgcn_global_load_lds(                                          \
        (const __attribute__((address_space(1))) void*)(PM + (size_t)((H)*128 + j*64)*Ksz + (T)*64), \
        (__attribute__((address_space(3))) void*)(L + (BOFF) + (MOFF) + (H)*16384 + j*8192 + dOff), \
        16, 0, 0); }

#define WAITV8  asm volatile("s_waitcnt vmcnt(8)"  ::: "memory");
#define WAITV10 asm volatile("s_waitcnt vmcnt(10)" ::: "memory");

#define PHASE(READS, MF, STG, WV)                                                \
    READS;                                                                       \
    STG;                                                                         \
    __builtin_amdgcn_sched_barrier(0);                                           \
    __builtin_amdgcn_s_barrier();                                                \
    asm volatile("s_waitcnt lgkmcnt(0)" ::: "memory");                           \
    __builtin_amdgcn_sched_barrier(0);                                           \
    __builtin_amdgcn_s_setprio(1);                                               \
    MF;                                                                          \
    __builtin_amdgcn_s_setprio(0);                                               \
    WV;                                                                          \
    __builtin_amdgcn_sched_barrier(0);                                           \
    __builtin_amdgcn_s_barrier();                                                \
    __builtin_amdgcn_sched_barrier(0);

__global__ __launch_bounds__(512, 2) void gemm_8p(const unsigned short* __restrict__ A,
                                                  const unsigned short* __restrict__ B,
                                                  float* __restrict__ C) {
    __shared__ __align__(16) unsigned char L[131072]; // 128 KiB

    const int tid  = threadIdx.x;
    const int lane = tid & 63;
    const int wid  = tid >> 6;
    const int wr   = wid >> 2;   // 0..1
    const int wc   = wid & 3;    // 0..3
    const int rowBase = blockIdx.y * 256;
    const int colBase = blockIdx.x * 256;

    // 32x32 frag read geometry (within 1KiB subtile, swizzled)
    const int hi16  = (lane >> 4) & 1;   // upper 16 rows of the 32-row frag
    const int laneT = (((lane & 15) * 64) + (((lane >> 5) & 1) * 16))
                      ^ (((lane >> 3) & 1) << 5);
    // stager inverse-swizzled per-lane source k-offset (verified involution)
    const int kloc = (lane & 1) * 8 + (((lane >> 1) ^ (lane >> 5)) & 1) * 16;
    const int r_st = lane >> 2;
    const int dOff = wid * 1024;

    const unsigned short* pAb = A + (size_t)(rowBase + (wid >> 1) * 16 + r_st) * Ksz + (wid & 1) * 32 + kloc;
    const unsigned short* pBb = B + (size_t)(colBase + (wid >> 1) * 16 + r_st) * Ksz + (wid & 1) * 32 + kloc;

    f32x16 acc[4][2] = {};
    short8 af[4], bf[2][4];

    // ---- prologue (R6 ledger): t0.{B.h0,A.h0,B.h1,A.h1} + t1.{B.h0,A.h1,B.h1} ----
    STAGE_H(pBb, 32768, 0,     0, 0);
    STAGE_H(pAb, 0,     0,     0, 0);
    STAGE_H(pBb, 32768, 0,     0, 1);
    STAGE_H(pAb, 0,     0,     0, 1);
    STAGE_H(pBb, 32768, 65536, 1, 0);
    STAGE_H(pAb, 0,     65536, 1, 1);
    STAGE_H(pBb, 32768, 65536, 1, 1);
    WAITV8                       // retires t0.{B.h0,A.h0,B.h1}; 8 stay in flight
    __builtin_amdgcn_sched_barrier(0);
    __builtin_amdgcn_s_barrier();
    __builtin_amdgcn_sched_barrier(0);

    for (int i = 0; i < 32; ++i) {
        const int t1 = 2 * i + 1;
        const int t2 = (i < 31) ? 2 * i + 2 : 62;  // clamp: last-iter stages are
        const int t3 = (i < 31) ? 2 * i + 3 : 62;  // dead writes into freed regions

        // tile t=2i in buf0: rowfrags 0,1 (A-half0) then 2,3 (A-half1);
        // tile t+1 in buf1: reversed 2,3 then 0,1. Stage slots/waits = R6.
        PHASE({ READ_B32(0); READ_A32(0, 0); }, MFMAS32(0), STAGE_H(pAb, 0,     65536, t1, 0), )        // P1
        PHASE(READ_A32(0, 1),                   MFMAS32(1), STAGE_H(pBb, 32768, 0,     t2, 0), WAITV10) // P2
        PHASE(READ_A32(0, 2),                   MFMAS32(2), STAGE_H(pAb, 0,     0,     t2, 0), )        // P3
        PHASE(READ_A32(0, 3),                   MFMAS32(3), STAGE_H(pBb, 32768, 0,     t2, 1), WAITV8)  // P4
        PHASE({ READ_B32(1); READ_A32(1, 2); }, MFMAS32(2), STAGE_H(pAb, 0,     0,     t2, 1), )        // P5
        PHASE(READ_A32(1, 3),                   MFMAS32(3), STAGE_H(pBb, 32768, 65536, t3, 0), WAITV10) // P6
        PHASE(READ_A32(1, 0),                   MFMAS32(0), STAGE_H(pAb, 0,     65536, t3, 1), )        // P7
        PHASE(READ_A32(1, 1),                   MFMAS32(1), STAGE_H(pBb, 32768, 65536, t3, 1), WAITV8)  // P8
    }

    // drain outstanding gload_lds before LDS teardown / endpgm
    asm volatile("s_waitcnt vmcnt(0)" ::: "memory");

    // epilogue: 32x32 C/D layout (m74/m101): col = lane&31,
    // row = (reg&3) + 8*(reg>>2) + 4*((lane>>5)&1)
    const int hi = (lane >> 5) & 1;
    const int ccol = colBase + wc * 64 + (lane & 31);
#pragma unroll
    for (int f = 0; f < 4; ++f)
#pragma unroll
        for (int n = 0; n < 2; ++n) {
            const int r0 = rowBase + f * 64 + wr * 32 + 4 * hi;
            float* cp = C + (size_t)r0 * Nsz + ccol + n * 32;
#pragma unroll
            for (int g = 0; g < 4; ++g)
#pragma unroll
                for (int j = 0; j < 4; ++j)
                    cp[(size_t)(g * 8 + j) * Nsz] = acc[f][n][g * 4 + j];
        }
}

// ---------------- fallback (ws too small): exact fp32, slow but correct ----------------
__global__ void gemm_naive(const float* __restrict__ x, const int* __restrict__ t,
                           const float* __restrict__ s, float* __restrict__ C) {
    size_t o = (size_t)blockIdx.x * blockDim.x + threadIdx.x;
    if (o >= (size_t)Msz * Nsz) return;
    int m = (int)(o / Nsz), n = (int)(o % Nsz);
    float acc = 0.f;
    for (int g = 0; g < Ksz / 128; ++g) {
        float sc = s[n * (Ksz / 128) + g];
        float p = 0.f;
        const float* xp = x + (size_t)m * Ksz + g * 128;
        const int* tp = t + (size_t)n * Ksz + g * 128;
        for (int k = 0; k < 128; ++k) p += xp[k] * (float)tp[k];
        acc += sc * p;
    }
    C[o] = acc;
}

extern "C" void kernel_launch(void* const* d_in, const int* in_sizes, int n_in,
                              void* d_out, int out_size, void* d_ws, size_t ws_size,
                              hipStream_t stream) {
    const float* x      = (const float*)d_in[0];
    const int*   tern   = (const int*)d_in[1];
    const float* scales = (const float*)d_in[2];
    float* out = (float*)d_out;

    const size_t aBytes = (size_t)Msz * Ksz * 2; // 64 MiB
    const size_t bBytes = (size_t)Nsz * Ksz * 2; // 32 MiB

    if (ws_size >= aBytes + bBytes) {
        unsigned short* Abf = (unsigned short*)d_ws;
        unsigned short* Bbf = (unsigned short*)((char*)d_ws + aBytes);
        prep<<<3072, 256, 0, stream>>>(x, tern, scales, Abf, Bbf);
        dim3 grid(Nsz / 256, Msz / 256);
        gemm_8p<<<grid, 512, 0, stream>>>(Abf, Bbf, out);
    } else {
        gemm_naive<<<(int)(((size_t)Msz * Nsz + 255) / 256), 256, 0, stream>>>(x, tern, scales, out);
    }
}